// Round 8
// baseline (1193.681 us; speedup 1.0000x reference)
//
#include <hip/hip_runtime.h>

// ---------------- problem constants ----------------
// VOCAB=50000, E=128, H=256, B=64, M=50, S=20, SQ=20, SEQEND=2, HOPS=3
//
// R12 -> R13: cut arch VGPRs so a wave's UNIFIED allocation fits 256.
//  - R12 refuted the LDS-residency theory (32 KB, occupancy still 11.7%).
//    Model now: trace VGPR_Count=224 is arch-only; +64 AGPR acc (unified
//    gfx950 file) = 288/wave -> floor(512/288)=1 wave/SIMD -> 1 block/CU.
//    Co-residency needs total<=256 => arch<=192.
//  - Staging regs 64 -> 16: h-read done in 4 sequential batches of 4 rows
//    (batch0 issued before the loop-top barrier, overlapping barrier+gi;
//    batches 1-3 issue->poll->stage re-using the same 16 VGPRs). ~3 extra
//    L2-RTTs/step exposed (second-order).
//  - Eos targets byte-packed: 16 ints -> 4 (-12 regs).
//  - WAR barrier moved to loop TOP (before gi): slowest poller gates only
//    the publish barrier (fixes R12's 512->554 regression).
//  - Readout: VGPR<=192 + Occupancy ~25% + gru_k ~300us confirms the
//    unified-file model; VGPR drop w/o occupancy gain refutes it.
//  - Unchanged: XCD-colocation swizzle, 128 half-chains depth<=30, single
//    32 KB xor-swizzled LDS h tile, tag-in-word exchange, bounded spins,
//    per-launch zeroing, fast sigmoid/tanh.

typedef __attribute__((ext_vector_type(8))) short bf16x8;
typedef __attribute__((ext_vector_type(4))) float f32x4;
typedef __attribute__((ext_vector_type(4))) unsigned u32x4;

#define SPIN_MAX 16384

#if defined(__has_builtin) && __has_builtin(__builtin_amdgcn_rcpf)
#define RCPF(x) __builtin_amdgcn_rcpf(x)
#else
#define RCPF(x) (1.f / (x))
#endif

__device__ __forceinline__ void spin_pause() {
#if defined(__has_builtin) && __has_builtin(__builtin_amdgcn_s_sleep)
  __builtin_amdgcn_s_sleep(1);
#else
  __builtin_amdgcn_s_nop(7);
#endif
}

__device__ __forceinline__ unsigned short f2bf(float f) {
  union { float f; unsigned u; } v; v.f = f;
  unsigned x = v.u;
  return (unsigned short)((x + 0x7fffu + ((x >> 16) & 1u)) >> 16);
}

__device__ __forceinline__ float sigm_fast(float x) {
  return RCPF(1.f + __expf(-x));
}
__device__ __forceinline__ float tanh_fast(float x) {
  return 2.f * RCPF(1.f + __expf(-2.f * x)) - 1.f;
}

// ---------------- prep: zero h-exchange buffers + eos index extraction ----------------
__global__ void prep_k(u32x4* __restrict__ zp, int nz4,
                       const int* __restrict__ story, const int* __restrict__ query,
                       int* __restrict__ idx_s, int* __restrict__ qidx) {
  int blk = blockIdx.x;
  if (blk * 256 < nz4) {
    int i = blk * 256 + threadIdx.x;
    if (i < nz4) zp[i] = (u32x4){0u, 0u, 0u, 0u};
  } else {
    int i = (blk - (nz4 + 255) / 256) * 256 + threadIdx.x;
    if (i < 3200) {                     // b*50+m
      const int* r = story + i * 20;
      int f = 19;
      for (int s = 19; s >= 0; --s) if (r[s] == 2) f = s;
      idx_s[i] = f;
    } else if (i < 3264) {
      int b = i - 3200;
      const int* r = query + b * 20;
      int f = 19;
      for (int s = 19; s >= 0; --s) if (r[s] == 2) f = s;
      qidx[b] = f;
    }
  }
}

// ---------------- embedding gather -> bf16 X buffers ----------------
// Xs: [1280][64 rows][128] bf16 (2 per uint) ; Xq: [20][64][128] bf16
__global__ void gather_k(const int* __restrict__ story, const int* __restrict__ query,
                         const float* __restrict__ embed,
                         unsigned* __restrict__ Xs, unsigned* __restrict__ Xq) {
  long long id = (long long)blockIdx.x * 256 + threadIdx.x;
  if (id < 5242880LL) {                 // 1280*64*64
    int e2 = (int)(id & 63);
    int m  = (int)((id >> 6) & 63);
    int t  = (int)(id >> 12);
    unsigned val = 0u;
    if (m < 50) {
      int b = t / 20, s = t - b * 20;
      int tok = story[(b * 50 + m) * 20 + s];
      const float* e = embed + (size_t)tok * 128 + e2 * 2;
      val = (unsigned)f2bf(e[0]) | ((unsigned)f2bf(e[1]) << 16);
    }
    Xs[id] = val;
  } else {
    long long id2 = id - 5242880LL;     // 20*64*64 = 81920
    int e2 = (int)(id2 & 63);
    int b  = (int)((id2 >> 6) & 63);
    int t  = (int)(id2 >> 12);
    int tok = query[b * 20 + t];
    const float* e = embed + (size_t)tok * 128 + e2 * 2;
    Xq[id2] = (unsigned)f2bf(e[0]) | ((unsigned)f2bf(e[1]) << 16);
  }
}

// ---------------- one GRU chain: 4 WGs x 4 waves; wave owns 16 cols, all 64 rows ------
// Exchange buffer hb (per chain): [parity 2][row 64][word 128] u64;
// word = (tag(32) << 32) | bf16-pair(32), tag = step+1.
// LDS s_h: single 32 KB tile [64 rows][64 u64], 16B-slot xor swizzle by row&7.
// Staging: 4 sequential batches of 4 rows (16 VGPRs peak instead of 64).
// tp[rt]: byte-packed eos target steps+1 (0 = never), byte i = elem i.
__device__ __forceinline__ void run_chain(
    const unsigned* __restrict__ X, int tokBase, int T,
    unsigned long long* __restrict__ hb,
    unsigned long long* __restrict__ s_h,
    const bf16x8 (&Bih)[3][4], const bf16x8 (&Bhh)[3][8],
    float br, float bz, float bin, float bhn,
    const int (&tp)[4], float* __restrict__ outp,
    int lane, int wave, int lo, int quad, int col) {
  union U4 { u32x4 v4; bf16x8 v; };
  const int e = lo & 7;                 // read-side LDS xor-swizzle key

  float h_own[4][4];
#pragma unroll
  for (int rt = 0; rt < 4; ++rt)
#pragma unroll
    for (int i = 0; i < 4; ++i) h_own[rt][i] = 0.f;

  for (int t = 0; t < T; ++t) {
    const unsigned* xt = X + (size_t)(tokBase + t) * 4096;
    f32x4 acc[4][3];   // r, z, i_n
    f32x4 acchn[4];    // h_n (r multiplies only this part)
#pragma unroll
    for (int rt = 0; rt < 4; ++rt) {
#pragma unroll
      for (int g = 0; g < 3; ++g) acc[rt][g] = (f32x4){0.f, 0.f, 0.f, 0.f};
      acchn[rt] = (f32x4){0.f, 0.f, 0.f, 0.f};
    }

    const unsigned long long* hs = hb + (size_t)((t - 1) & 1) * 8192;
    unsigned long long stg0[4], stg1[4];
    if (t > 0) {
      // ---- issue batch 0 (rows wave*16 + 0..3); overlaps barrier + gi ----
#pragma unroll
      for (int j = 0; j < 4; ++j) {
        const unsigned long long* p = hs + (wave * 16 + j) * 128 + lane * 2;
        stg0[j] = __hip_atomic_load(p,     __ATOMIC_RELAXED, __HIP_MEMORY_SCOPE_AGENT);
        stg1[j] = __hip_atomic_load(p + 1, __ATOMIC_RELAXED, __HIP_MEMORY_SCOPE_AGENT);
      }
      asm volatile("" ::: "memory");
      __syncthreads();  // WAR (loop top): all prior-step LDS reads complete
    }

    // ---- gi MFMAs (h-independent; overlap batch-0 flight) ----
#pragma unroll
    for (int rt = 0; rt < 4; ++rt) {
#pragma unroll
      for (int kt = 0; kt < 4; ++kt) {
        U4 ax;
        ax.v4 = *(const u32x4*)(xt + (rt * 16 + lo) * 64 + kt * 16 + quad * 4);
#pragma unroll
        for (int g = 0; g < 3; ++g)
          acc[rt][g] = __builtin_amdgcn_mfma_f32_16x16x32_bf16(
              ax.v, Bih[g][kt], acc[rt][g], 0, 0, 0);
      }
    }

    if (t > 0) {
      const unsigned want = (unsigned)t;
      // ---- 4 batches: (issue) -> poll -> stage, re-using the same 16 VGPRs ----
#pragma unroll
      for (int bb = 0; bb < 4; ++bb) {
        if (bb > 0) {
#pragma unroll
          for (int j = 0; j < 4; ++j) {
            const unsigned long long* p =
                hs + (wave * 16 + bb * 4 + j) * 128 + lane * 2;
            stg0[j] = __hip_atomic_load(p,     __ATOMIC_RELAXED, __HIP_MEMORY_SCOPE_AGENT);
            stg1[j] = __hip_atomic_load(p + 1, __ATOMIC_RELAXED, __HIP_MEMORY_SCOPE_AGENT);
          }
        }
        for (int it = 0; it < SPIN_MAX; ++it) {
          bool ok = true;
#pragma unroll
          for (int j = 0; j < 4; ++j)
            ok &= ((unsigned)(stg0[j] >> 32) == want) &
                  ((unsigned)(stg1[j] >> 32) == want);
          if (__all(ok)) break;
          spin_pause();
#pragma unroll
          for (int j = 0; j < 4; ++j) {
            const unsigned long long* p =
                hs + (wave * 16 + bb * 4 + j) * 128 + lane * 2;
            stg0[j] = __hip_atomic_load(p,     __ATOMIC_RELAXED, __HIP_MEMORY_SCOPE_AGENT);
            stg1[j] = __hip_atomic_load(p + 1, __ATOMIC_RELAXED, __HIP_MEMORY_SCOPE_AGENT);
          }
        }
#pragma unroll
        for (int j = 0; j < 4; ++j) {
          int row = wave * 16 + bb * 4 + j;
          unsigned long long v =
              ((unsigned long long)(unsigned)stg1[j] << 32) | (unsigned)stg0[j];
          s_h[row * 64 + (((lane >> 1) ^ (row & 7)) * 2 + (lane & 1))] = v;
        }
      }
      __syncthreads();                  // publish staged tile
      const unsigned* sh32 = (const unsigned*)s_h;
#pragma unroll
      for (int kt = 0; kt < 8; ++kt) {
#pragma unroll
        for (int rt = 0; rt < 4; ++rt) {
          U4 ah;
          ah.v4 = *(const u32x4*)(sh32 + (rt * 16 + lo) * 128 +
                                  (((kt * 4 + quad) ^ e) << 2));
          acc[rt][0] = __builtin_amdgcn_mfma_f32_16x16x32_bf16(
              ah.v, Bhh[0][kt], acc[rt][0], 0, 0, 0);
          acc[rt][1] = __builtin_amdgcn_mfma_f32_16x16x32_bf16(
              ah.v, Bhh[1][kt], acc[rt][1], 0, 0, 0);
          acchn[rt] = __builtin_amdgcn_mfma_f32_16x16x32_bf16(
              ah.v, Bhh[2][kt], acchn[rt], 0, 0, 0);
        }
      }
    }

    // ---- GRU gates (fp32, fast transcendentals) ----
#pragma unroll
    for (int rt = 0; rt < 4; ++rt) {
#pragma unroll
      for (int i = 0; i < 4; ++i) {
        float r = sigm_fast(acc[rt][0][i] + br);
        float z = sigm_fast(acc[rt][1][i] + bz);
        float n = tanh_fast(acc[rt][2][i] + bin + r * (acchn[rt][i] + bhn));
        h_own[rt][i] = (1.f - z) * n + z * h_own[rt][i];
      }
    }

    // ---- publish tagged h2 (fire-and-forget); skip on final step ----
    if (t + 1 < T) {
      unsigned long long* hd = hb + (size_t)(t & 1) * 8192;
      const unsigned long long tag = (unsigned long long)(unsigned)(t + 1) << 32;
#pragma unroll
      for (int rt = 0; rt < 4; ++rt) {
#pragma unroll
        for (int i = 0; i < 4; ++i) {
          unsigned short mb = f2bf(h_own[rt][i]);
          int other = __shfl_xor((int)(unsigned)mb, 1);
          if ((lane & 1) == 0) {
            unsigned pack = (unsigned)mb | (((unsigned)other & 0xffffu) << 16);
            __hip_atomic_store(hd + (rt * 16 + quad * 4 + i) * 128 + (col >> 1),
                               tag | (unsigned long long)pack,
                               __ATOMIC_RELAXED, __HIP_MEMORY_SCOPE_AGENT);
          }
        }
      }
    }

    // ---- eos extraction (byte-packed reg-compare, off critical path) ----
#pragma unroll
    for (int rt = 0; rt < 4; ++rt)
#pragma unroll
      for (int i = 0; i < 4; ++i) {
        if (((tp[rt] >> (8 * i)) & 255) == t + 1) {
          int m = rt * 16 + quad * 4 + i;
          outp[(size_t)m * 256 + col] = h_own[rt][i];
        }
      }
  }
}

// ---------------- warm-start chain GRU: grid 512 = 128 half-chains x 4 WGs -------------
// blockIdx remap: xcd = x&7, slot = x>>3; chain c = xcd + 8*(slot>>2), wg4 = slot&3.
// All 4 WGs of a chain share x%8 -> same XCD under round-robin dispatch.
__global__ __launch_bounds__(256, 1) void gru_k(
    const float* __restrict__ w_ih, const float* __restrict__ w_hh,
    const float* __restrict__ b_ih, const float* __restrict__ b_hh,
    const unsigned* __restrict__ Xs, const unsigned* __restrict__ Xq,
    unsigned long long* hbs, unsigned long long* hbq,
    const int* __restrict__ idx_s, const int* __restrict__ qidx,
    float* __restrict__ mem_slots, float* __restrict__ real_q) {
  __shared__ unsigned long long s_h[4096];  // 32 KB single h tile
  const int tid = threadIdx.x;
  const int x = blockIdx.x;
  const int c = (x & 7) + 8 * (x >> 5);     // chain 0..127 (xcd + 8*(slot>>2))
  const int wg4 = (x >> 3) & 3;             // WG within chain
  const int b = c >> 1;                     // batch/segment 0..63
  const int half = c & 1;                   // which 10-token half of the segment
  const int lane = tid & 63;
  const int wave = tid >> 6;
  const int lo = lane & 15;
  const int quad = lane >> 4;
  const int slice = wg4 * 4 + wave;         // 0..15 col-slice of the chain
  const int col = slice * 16 + lo;          // this lane's hidden dim

  // ---- loop-invariant weight B-fragments (bf16) in registers ----
  bf16x8 Bih[3][4], Bhh[3][8];
  for (int g = 0; g < 3; ++g) {
    const float* wr = w_ih + (size_t)(g * 256 + col) * 128;
    for (int kt = 0; kt < 4; ++kt) {
      const float* pp = wr + kt * 32 + quad * 8;
      union { unsigned short us[8]; bf16x8 v; } u;
#pragma unroll
      for (int j = 0; j < 8; ++j) u.us[j] = f2bf(pp[j]);
      Bih[g][kt] = u.v;
    }
    const float* wr2 = w_hh + (size_t)(g * 256 + col) * 256;
    for (int kt = 0; kt < 8; ++kt) {
      const float* pp = wr2 + kt * 32 + quad * 8;
      union { unsigned short us[8]; bf16x8 v; } u;
#pragma unroll
      for (int j = 0; j < 8; ++j) u.us[j] = f2bf(pp[j]);
      Bhh[g][kt] = u.v;
    }
  }
  const float br  = b_ih[col]       + b_hh[col];
  const float bz  = b_ih[256 + col] + b_hh[256 + col];
  const float bin = b_ih[512 + col];
  const float bhn = b_hh[512 + col];

  // ---- half-segment chain parameters (every output warmed >=20 steps) ----
  // half 0 covers story steps s in [0,10); half 1 covers s in [10,20).
  int tokBase, warm, T;
  if (half == 0) {
    if (b == 0) { tokBase = 0;            warm = 0;  T = 10; }
    else        { tokBase = (b - 1) * 20; warm = 20; T = 30; }
  } else {
    if (b == 0) { tokBase = 0;            warm = 10; T = 20; }
    else        { tokBase = b * 20 - 10;  warm = 20; T = 30; }
  }
  const int sLo = half * 10, sHi = sLo + 10, tOff = warm - sLo;

  // ---- story chain ----
  {
    const int* eb = idx_s + b * 50;
    int tp[4];
#pragma unroll
    for (int rt = 0; rt < 4; ++rt) {
      int v = 0;
#pragma unroll
      for (int i = 0; i < 4; ++i) {
        int m = rt * 16 + quad * 4 + i;
        int tv = 0;                       // 0 = never fires
        if (m < 50) {
          int s = eb[m];
          if (s >= sLo && s < sHi) tv = s + tOff + 1;   // compare vs t+1
        }
        v |= tv << (8 * i);
      }
      tp[rt] = v;
    }
    run_chain(Xs, tokBase, T, hbs + (size_t)c * 16384, s_h,
              Bih, Bhh, br, bz, bin, bhn, tp,
              mem_slots + (size_t)b * 50 * 256,
              lane, wave, lo, quad, col);
  }

  // ---- query chain on chain 0's WG quad (its story chain is only 10 steps) ----
  if (c == 0) {
    __syncthreads();
    int tp[4];
#pragma unroll
    for (int rt = 0; rt < 4; ++rt) {
      int v = 0;
#pragma unroll
      for (int i = 0; i < 4; ++i)
        v |= (qidx[rt * 16 + quad * 4 + i] + 1) << (8 * i);
      tp[rt] = v;
    }
    run_chain(Xq, 0, 20, hbq, s_h,
              Bih, Bhh, br, bz, bin, bhn, tp, real_q,
              lane, wave, lo, quad, col);
  }
}

// ---------------- mem_key = memory_slots @ w_m^T  [3200,256]x[256,256] ----------------
__global__ __launch_bounds__(256) void memkey_k(const float* __restrict__ slots,
                                                const float* __restrict__ w_m,
                                                float* __restrict__ mem_key) {
  __shared__ float A[4096];
  int tid = threadIdx.x;
  int r0 = blockIdx.x * 16;
  for (int i = tid; i < 4096; i += 256) A[i] = slots[(size_t)r0 * 256 + i];
  __syncthreads();
  float acc[16];
#pragma unroll
  for (int r = 0; r < 16; ++r) acc[r] = 0.f;
  const float* wr = w_m + (size_t)tid * 256;
  for (int k = 0; k < 256; ++k) {
    float wv = wr[k];
#pragma unroll
    for (int r = 0; r < 16; ++r) acc[r] += A[r * 256 + k] * wv;
  }
  for (int r = 0; r < 16; ++r) mem_key[(size_t)(r0 + r) * 256 + tid] = acc[r];
}

// ---------------- 3-hop attention over memory slots (one block per b) ----------------
__global__ __launch_bounds__(256) void hops_k(const float* __restrict__ mem_key,
                                              const float* __restrict__ slots,
                                              const float* __restrict__ rq,
                                              const float* __restrict__ ft_w1,
                                              const float* __restrict__ ft_b1,
                                              const float* __restrict__ ft_w2,
                                              const float* __restrict__ ft_b2,
                                              float* __restrict__ bufs) {
  int b = blockIdx.x;
  int tid = threadIdx.x;
  int lane = tid & 63;
  int wv = tid >> 6;
  __shared__ float ok[256], attn[64], bufl[256], h1[256];
  ok[tid] = rq[(size_t)b * 256 + tid];
  __syncthreads();
  const float* key = mem_key + (size_t)b * 50 * 256;
  const float* slt = slots + (size_t)b * 50 * 256;
  for (int hop = 0; hop < 3; ++hop) {
    for (int m = wv; m < 50; m += 4) {
      const float* kr = key + m * 256;
      float p = kr[lane] * ok[lane] + kr[lane + 64] * ok[lane + 64] +
                kr[lane + 128] * ok[lane + 128] + kr[lane + 192] * ok[lane + 192];
      for (int off = 32; off; off >>= 1) p += __shfl_down(p, off);
      if (lane == 0) attn[m] = p * 0.0625f;   // scale = 1/sqrt(256)
    }
    __syncthreads();
    if (tid == 0) {
      float mx = -1e30f;
      for (int m = 0; m < 50; ++m) mx = fmaxf(mx, attn[m]);
      float sm = 0.f;
      for (int m = 0; m < 50; ++m) { float e = __expf(attn[m] - mx); attn[m] = e; sm += e; }
      float inv = 1.f / sm;
      for (int m = 0; m < 50; ++m) attn[m] *= inv;
    }
    __syncthreads();
    float acc = 0.f;
    for (int m = 0; m < 50; ++m) acc += attn[m] * slt[m * 256 + tid];
    bufl[tid] = acc;
    bufs[(size_t)(b * 3 + hop) * 256 + tid] = acc;
    __syncthreads();
    float a1 = ft_b1[tid];
    const float* wr = ft_w1 + (size_t)tid * 256;
    for (int k = 0; k < 256; ++k) a1 += wr[k] * bufl[k];
    h1[tid] = fmaxf(a1, 0.f);
    __syncthreads();
    float a2 = ft_b2[tid];
    const float* w2r = ft_w2 + (size_t)tid * 256;
    for (int k = 0; k < 256; ++k) a2 += w2r[k] * h1[k];
    __syncthreads();
    ok[tid] = a2;
    __syncthreads();
  }
}

// ---------------- relation layer 1: t1 = relu(comb @ g_w1^T + g_b1) [576,768] ----------------
__global__ __launch_bounds__(256) void g1_k(const float* __restrict__ bufs,
                                            const float* __restrict__ rq,
                                            const float* __restrict__ w,
                                            const float* __restrict__ bias,
                                            float* __restrict__ out) {
  __shared__ float A[4 * 768];
  int tid = threadIdx.x;
  int r0 = blockIdx.x * 4;
  for (int i = tid; i < 4 * 768; i += 256) {
    int row = r0 + i / 768, k = i % 768;
    int bb = row / 9, p = row % 9;
    float v;
    if (k < 256)      v = bufs[(size_t)(bb * 3 + p % 3) * 256 + k];
    else if (k < 512) v = bufs[(size_t)(bb * 3 + p / 3) * 256 + (k - 256)];
    else              v = rq[(size_t)bb * 256 + (k - 512)];
    A[i] = v;
  }
  __syncthreads();
  for (int cc = 0; cc < 3; ++cc) {
    int c = cc * 256 + tid;
    float a0 = 0.f, a1 = 0.f, a2 = 0.f, a3 = 0.f;
    const float* wr = w + (size_t)c * 768;
    for (int k = 0; k < 768; ++k) {
      float wvl = wr[k];
      a0 += A[k] * wvl; a1 += A[768 + k] * wvl;
      a2 += A[1536 + k] * wvl; a3 += A[2304 + k] * wvl;
    }
    float bv = bias[c];
    out[(size_t)(r0 + 0) * 768 + c] = fmaxf(a0 + bv, 0.f);
    out[(size_t)(r0 + 1) * 768 + c] = fmaxf(a1 + bv, 0.f);
    out[(size_t)(r0 + 2) * 768 + c] = fmaxf(a2 + bv, 0.f);
    out[(size_t)(r0 + 3) * 768 + c] = fmaxf(a3 + bv, 0.f);
  }
}

// ---------------- relation layer 2: t2 = relu(t1 @ g_w2^T + g_b2) ----------------
__global__ __launch_bounds__(256) void g2_k(const float* __restrict__ t1,
                                            const float* __restrict__ w,
                                            const float* __restrict__ bias,
                                            float* __restrict__ out) {
  __shared__ float A[4 * 768];
  int tid = threadIdx.x;
  int r0 = blockIdx.x * 4;
  for (int i = tid; i < 4 * 768; i += 256) A[i] = t1[(size_t)r0 * 768 + i];
  __syncthreads();
  for (int cc = 0; cc < 3; ++cc) {
    int c = cc * 256 + tid;
    float a0 = 0.f, a1 = 0.f, a2 = 0.f, a3 = 0.f;
    const float* wr = w + (size_t)c * 768;
    for (int k = 0; k < 768; ++k) {
      float wvl = wr[k];
      a0 += A[k] * wvl; a1 += A[768 + k] * wvl;
      a2 += A[1536 + k] * wvl; a3 += A[2304 + k] * wvl;
    }
    float bv = bias[c];
    out[(size_t)(r0 + 0) * 768 + c] = fmaxf(a0 + bv, 0.f);
    out[(size_t)(r0 + 1) * 768 + c] = fmaxf(a1 + bv, 0.f);
    out[(size_t)(r0 + 2) * 768 + c] = fmaxf(a2 + bv, 0.f);
    out[(size_t)(r0 + 3) * 768 + c] = fmaxf(a3 + bv, 0.f);
  }
}

// ---------------- g-sum + f MLP -> reason [64,256] ----------------
__global__ __launch_bounds__(256) void reason_k(const float* __restrict__ t2,
                                                const float* __restrict__ f_w1,
                                                const float* __restrict__ f_b1,
                                                const float* __restrict__ f_w2,
                                                const float* __restrict__ f_b2,
                                                float* __restrict__ reason) {
  int b = blockIdx.x;
  int tid = threadIdx.x;
  __shared__ float gs[768], h1[768];
  for (int j = tid; j < 768; j += 256) {
    float s = 0.f;
    for (int p = 0; p < 9; ++p) s += t2[(size_t)(b * 9 + p) * 768 + j];
    gs[j] = s;
  }
  __syncthreads();
  for (int jc = 0; jc < 3; ++jc) {
    int j = jc * 256 + tid;
    float a = f_b1[j];
    const float* wr = f_w1 + (size_t)j * 768;
    for (int k = 0; k < 768; ++k) a += wr[k] * gs[k];
    h1[j] = fmaxf(a, 0.f);
  }
  __syncthreads();
  {
    int j = tid;
    float a = f_b2[j];
    const float* wr = f_w2 + (size_t)j * 768;
    for (int k = 0; k < 768; ++k) a += wr[k] * h1[k];
    reason[(size_t)b * 256 + j] = a;
  }
}

// ---------------- out = reason @ v_w^T  [64,50000] ----------------
__global__ __launch_bounds__(256) void vocab_k(const float* __restrict__ reason,
                                               const float* __restrict__ v_w,
                                               float* __restrict__ out) {
  __shared__ float A[32 * 256];
  int tid = threadIdx.x;
  int c = blockIdx.x * 256 + tid;
  for (int bc = 0; bc < 2; ++bc) {
    for (int i = tid; i < 32 * 256; i += 256) A[i] = reason[bc * 32 * 256 + i];
    __syncthreads();
    if (c < 50000) {
      float acc[32];
#pragma unroll
      for (int r = 0; r < 32; ++r) acc[r] = 0.f;
      const float* wr = v_w + (size_t)c * 256;
      for (int k = 0; k < 256; ++k) {
        float wvl = wr[k];
#pragma unroll
        for (int r = 0; r < 32; ++r) acc[r] += A[r * 256 + k] * wvl;
      }
      for (int r = 0; r < 32; ++r) out[(size_t)(bc * 32 + r) * 50000 + c] = acc[r];
    }
    __syncthreads();
  }
}

// ---------------- launch ----------------
extern "C" void kernel_launch(void* const* d_in, const int* in_sizes, int n_in,
                              void* d_out, int out_size, void* d_ws, size_t ws_size,
                              hipStream_t stream) {
  (void)in_sizes; (void)n_in; (void)out_size; (void)ws_size;
  const int*   story = (const int*)d_in[0];
  const int*   query = (const int*)d_in[1];
  const float* embed = (const float*)d_in[2];
  const float* w_ih  = (const float*)d_in[3];
  const float* w_hh  = (const float*)d_in[4];
  const float* b_ih  = (const float*)d_in[5];
  const float* b_hh  = (const float*)d_in[6];
  const float* w_m   = (const float*)d_in[7];
  const float* ft_w1 = (const float*)d_in[8];
  const float* ft_b1 = (const float*)d_in[9];
  const float* ft_w2 = (const float*)d_in[10];
  const float* ft_b2 = (const float*)d_in[11];
  const float* g_w1  = (const float*)d_in[12];
  const float* g_b1  = (const float*)d_in[13];
  const float* g_w2  = (const float*)d_in[14];
  const float* g_b2  = (const float*)d_in[15];
  const float* f_w1  = (const float*)d_in[16];
  const float* f_b1  = (const float*)d_in[17];
  const float* f_w2  = (const float*)d_in[18];
  const float* f_b2  = (const float*)d_in[19];
  const float* v_w   = (const float*)d_in[20];
  float* out = (float*)d_out;

  char* ws = (char*)d_ws;
  unsigned* Xs = (unsigned*)(ws + 0);               // 20,971,520 B
  unsigned* Xq = (unsigned*)(ws + 20971520);        //    327,680 B
  unsigned long long* hbs =
      (unsigned long long*)(ws + 21299200);         // 16,777,216 B (128 x 16384 u64)
  unsigned long long* hbq =
      (unsigned long long*)(ws + 38076416);         //    131,072 B
  int*      idx_s   = (int*)(ws + 38207488);        //     12,800 B
  int*      qidx    = (int*)(ws + 38220288);        //        256 B
  float*    mslots  = (float*)(ws + 38220544);      //  3,276,800 B
  float*    real_q  = (float*)(ws + 41497344);      //     65,536 B  (end ~41.6 MB)
  // post-GRU overlay inside the (dead) Xs region:
  float*    mem_key = (float*)(ws + 0);             //  3,276,800 B
  float*    bufs    = (float*)(ws + 3276800);       //    196,608 B
  float*    t1      = (float*)(ws + 3473408);       //  1,769,472 B
  float*    t2      = (float*)(ws + 5242880);       //  1,769,472 B
  float*    reason  = (float*)(ws + 7012352);       //     65,536 B

  // prep: zero hbs+hbq (1,056,768 u32x4 -> 4128 blocks) + eos idx (13 blocks)
  prep_k<<<4141, 256, 0, stream>>>((u32x4*)(ws + 21299200), 1056768,
                                   story, query, idx_s, qidx);
  gather_k<<<20800, 256, 0, stream>>>(story, query, embed, Xs, Xq);
  gru_k<<<512, 256, 0, stream>>>(w_ih, w_hh, b_ih, b_hh, Xs, Xq, hbs, hbq,
                                 idx_s, qidx, mslots, real_q);
  memkey_k<<<200, 256, 0, stream>>>(mslots, w_m, mem_key);
  hops_k<<<64, 256, 0, stream>>>(mem_key, mslots, real_q,
                                 ft_w1, ft_b1, ft_w2, ft_b2, bufs);
  g1_k<<<144, 256, 0, stream>>>(bufs, real_q, g_w1, g_b1, t1);
  g2_k<<<144, 256, 0, stream>>>(t1, g_w2, g_b2, t2);
  reason_k<<<64, 256, 0, stream>>>(t2, f_w1, f_b1, f_w2, f_b2, reason);
  vocab_k<<<196, 256, 0, stream>>>(reason, v_w, out);
}

// Round 9
// 997.379 us; speedup vs baseline: 1.1968x; 1.1968x over previous
//
#include <hip/hip_runtime.h>

// ---------------- problem constants ----------------
// VOCAB=50000, E=128, H=256, B=64, M=50, S=20, SQ=20, SEQEND=2, HOPS=3
//
// R13 -> R14: stop fighting the register allocator; take the best verified
// configuration.
//  - Ledger: per-step ~8.5us with XCD-colocation (R11/R13) vs 10.1 without
//    (R6). At 1 block/CU (unified-file: 212arch+64acc > 256/wave), the
//    128-half-chain grid (512 WGs) runs as TWO serialized 30-step phases =
//    60-step path -- strictly worse than 64 full chains' 40-step path.
//    Two rounds of VGPR-shaving missed their 192 target; abandoned.
//  - R14 = 64 chains x 4 WGs = 256 blocks, single phase (R6-proven
//    residency), composed with every measured win: XCD-colocation swizzle,
//    R11 double-buffered 64KB LDS h tile + ONE barrier/step, full 32-reg
//    staging (R13's batching cost ~0.5us/step), tag-in-word exchange,
//    fast sigmoid/tanh, byte-packed eos targets, merged prep kernel.
//  - Predicted: gru_k ~340-380us (40 steps x ~8.5us); total ~1000us.

typedef __attribute__((ext_vector_type(8))) short bf16x8;
typedef __attribute__((ext_vector_type(4))) float f32x4;
typedef __attribute__((ext_vector_type(4))) unsigned u32x4;

#define SPIN_MAX 16384

#if defined(__has_builtin) && __has_builtin(__builtin_amdgcn_rcpf)
#define RCPF(x) __builtin_amdgcn_rcpf(x)
#else
#define RCPF(x) (1.f / (x))
#endif

__device__ __forceinline__ void spin_pause() {
#if defined(__has_builtin) && __has_builtin(__builtin_amdgcn_s_sleep)
  __builtin_amdgcn_s_sleep(1);
#else
  __builtin_amdgcn_s_nop(7);
#endif
}

__device__ __forceinline__ unsigned short f2bf(float f) {
  union { float f; unsigned u; } v; v.f = f;
  unsigned x = v.u;
  return (unsigned short)((x + 0x7fffu + ((x >> 16) & 1u)) >> 16);
}

__device__ __forceinline__ float sigm_fast(float x) {
  return RCPF(1.f + __expf(-x));
}
__device__ __forceinline__ float tanh_fast(float x) {
  return 2.f * RCPF(1.f + __expf(-2.f * x)) - 1.f;
}

// ---------------- prep: zero h-exchange buffers + eos index extraction ----------------
__global__ void prep_k(u32x4* __restrict__ zp, int nz4,
                       const int* __restrict__ story, const int* __restrict__ query,
                       int* __restrict__ idx_s, int* __restrict__ qidx) {
  int blk = blockIdx.x;
  if (blk * 256 < nz4) {
    int i = blk * 256 + threadIdx.x;
    if (i < nz4) zp[i] = (u32x4){0u, 0u, 0u, 0u};
  } else {
    int i = (blk - (nz4 + 255) / 256) * 256 + threadIdx.x;
    if (i < 3200) {                     // b*50+m
      const int* r = story + i * 20;
      int f = 19;
      for (int s = 19; s >= 0; --s) if (r[s] == 2) f = s;
      idx_s[i] = f;
    } else if (i < 3264) {
      int b = i - 3200;
      const int* r = query + b * 20;
      int f = 19;
      for (int s = 19; s >= 0; --s) if (r[s] == 2) f = s;
      qidx[b] = f;
    }
  }
}

// ---------------- embedding gather -> bf16 X buffers ----------------
// Xs: [1280][64 rows][128] bf16 (2 per uint) ; Xq: [20][64][128] bf16
__global__ void gather_k(const int* __restrict__ story, const int* __restrict__ query,
                         const float* __restrict__ embed,
                         unsigned* __restrict__ Xs, unsigned* __restrict__ Xq) {
  long long id = (long long)blockIdx.x * 256 + threadIdx.x;
  if (id < 5242880LL) {                 // 1280*64*64
    int e2 = (int)(id & 63);
    int m  = (int)((id >> 6) & 63);
    int t  = (int)(id >> 12);
    unsigned val = 0u;
    if (m < 50) {
      int b = t / 20, s = t - b * 20;
      int tok = story[(b * 50 + m) * 20 + s];
      const float* e = embed + (size_t)tok * 128 + e2 * 2;
      val = (unsigned)f2bf(e[0]) | ((unsigned)f2bf(e[1]) << 16);
    }
    Xs[id] = val;
  } else {
    long long id2 = id - 5242880LL;     // 20*64*64 = 81920
    int e2 = (int)(id2 & 63);
    int b  = (int)((id2 >> 6) & 63);
    int t  = (int)(id2 >> 12);
    int tok = query[b * 20 + t];
    const float* e = embed + (size_t)tok * 128 + e2 * 2;
    Xq[id2] = (unsigned)f2bf(e[0]) | ((unsigned)f2bf(e[1]) << 16);
  }
}

// ---------------- one GRU chain: 4 WGs x 4 waves; wave owns 16 cols, all 64 rows ------
// Exchange buffer hb (per chain): [parity 2][row 64][word 128] u64;
// word = (tag(32) << 32) | bf16-pair(32), tag = step+1.
// LDS s_h: double-buffered [2][64 rows][64 u64]; 16B-slot xor swizzle by row&7;
// ONE barrier/step (dbuf alternation makes WAR impossible: step t+2's writes
// to buffer t&1 are gated by barrier t+1, which follows step t's reads).
// tp[rt]: byte-packed eos target steps+1 (0 = never), byte i = elem i.
__device__ __forceinline__ void run_chain(
    const unsigned* __restrict__ X, int tokBase, int T,
    unsigned long long* __restrict__ hb,
    unsigned long long* __restrict__ s_h,
    const bf16x8 (&Bih)[3][4], const bf16x8 (&Bhh)[3][8],
    float br, float bz, float bin, float bhn,
    const int (&tp)[4], float* __restrict__ outp,
    int lane, int wave, int lo, int quad, int col) {
  union U4 { u32x4 v4; bf16x8 v; };
  const int e = lo & 7;                 // read-side LDS xor-swizzle key

  float h_own[4][4];
#pragma unroll
  for (int rt = 0; rt < 4; ++rt)
#pragma unroll
    for (int i = 0; i < 4; ++i) h_own[rt][i] = 0.f;

  for (int t = 0; t < T; ++t) {
    const unsigned* xt = X + (size_t)(tokBase + t) * 4096;
    f32x4 acc[4][3];   // r, z, i_n
    f32x4 acchn[4];    // h_n (r multiplies only this part)
#pragma unroll
    for (int rt = 0; rt < 4; ++rt) {
#pragma unroll
      for (int g = 0; g < 3; ++g) acc[rt][g] = (f32x4){0.f, 0.f, 0.f, 0.f};
      acchn[rt] = (f32x4){0.f, 0.f, 0.f, 0.f};
    }

    unsigned long long stg0[16], stg1[16];
    if (t > 0) {
      // ---- issue tagged h loads (this wave's 16-row quarter, full 256 cols) ----
      const unsigned long long* hs = hb + (size_t)((t - 1) & 1) * 8192;
#pragma unroll
      for (int j = 0; j < 16; ++j) {
        const unsigned long long* p = hs + (wave * 16 + j) * 128 + lane * 2;
        stg0[j] = __hip_atomic_load(p,     __ATOMIC_RELAXED, __HIP_MEMORY_SCOPE_AGENT);
        stg1[j] = __hip_atomic_load(p + 1, __ATOMIC_RELAXED, __HIP_MEMORY_SCOPE_AGENT);
      }
      asm volatile("" ::: "memory");    // keep load issue ahead of the gi block
    }

    // ---- gi MFMAs (h-independent; overlap the load flight) ----
#pragma unroll
    for (int rt = 0; rt < 4; ++rt) {
#pragma unroll
      for (int kt = 0; kt < 4; ++kt) {
        U4 ax;
        ax.v4 = *(const u32x4*)(xt + (rt * 16 + lo) * 64 + kt * 16 + quad * 4);
#pragma unroll
        for (int g = 0; g < 3; ++g)
          acc[rt][g] = __builtin_amdgcn_mfma_f32_16x16x32_bf16(
              ax.v, Bih[g][kt], acc[rt][g], 0, 0, 0);
      }
    }

    if (t > 0) {
      // ---- poll: the load IS the sync (tag rides with the data) ----
      const unsigned want = (unsigned)t;
      const unsigned long long* hs = hb + (size_t)((t - 1) & 1) * 8192;
      for (int it = 0; it < SPIN_MAX; ++it) {
        bool ok = true;
#pragma unroll
        for (int j = 0; j < 16; ++j)
          ok &= ((unsigned)(stg0[j] >> 32) == want) &
                ((unsigned)(stg1[j] >> 32) == want);
        if (__all(ok)) break;
        spin_pause();
#pragma unroll
        for (int j = 0; j < 16; ++j) {
          const unsigned long long* p = hs + (wave * 16 + j) * 128 + lane * 2;
          stg0[j] = __hip_atomic_load(p,     __ATOMIC_RELAXED, __HIP_MEMORY_SCOPE_AGENT);
          stg1[j] = __hip_atomic_load(p + 1, __ATOMIC_RELAXED, __HIP_MEMORY_SCOPE_AGENT);
        }
      }
      // ---- stage to LDS buffer (t&1), xor-swizzled 16B slots ----
      unsigned long long* sbuf = s_h + (size_t)(t & 1) * 4096;
#pragma unroll
      for (int j = 0; j < 16; ++j) {
        int row = wave * 16 + j;
        unsigned long long v =
            ((unsigned long long)(unsigned)stg1[j] << 32) | (unsigned)stg0[j];
        sbuf[row * 64 + (((lane >> 1) ^ (j & 7)) * 2 + (lane & 1))] = v;
      }
      __syncthreads();
      const unsigned* sh32 = (const unsigned*)sbuf;
#pragma unroll
      for (int kt = 0; kt < 8; ++kt) {
#pragma unroll
        for (int rt = 0; rt < 4; ++rt) {
          U4 ah;
          ah.v4 = *(const u32x4*)(sh32 + (rt * 16 + lo) * 128 +
                                  (((kt * 4 + quad) ^ e) << 2));
          acc[rt][0] = __builtin_amdgcn_mfma_f32_16x16x32_bf16(
              ah.v, Bhh[0][kt], acc[rt][0], 0, 0, 0);
          acc[rt][1] = __builtin_amdgcn_mfma_f32_16x16x32_bf16(
              ah.v, Bhh[1][kt], acc[rt][1], 0, 0, 0);
          acchn[rt] = __builtin_amdgcn_mfma_f32_16x16x32_bf16(
              ah.v, Bhh[2][kt], acchn[rt], 0, 0, 0);
        }
      }
    }

    // ---- GRU gates (fp32, fast transcendentals) ----
#pragma unroll
    for (int rt = 0; rt < 4; ++rt) {
#pragma unroll
      for (int i = 0; i < 4; ++i) {
        float r = sigm_fast(acc[rt][0][i] + br);
        float z = sigm_fast(acc[rt][1][i] + bz);
        float n = tanh_fast(acc[rt][2][i] + bin + r * (acchn[rt][i] + bhn));
        h_own[rt][i] = (1.f - z) * n + z * h_own[rt][i];
      }
    }

    // ---- publish tagged h2 (fire-and-forget); skip on final step ----
    if (t + 1 < T) {
      unsigned long long* hd = hb + (size_t)(t & 1) * 8192;
      const unsigned long long tag = (unsigned long long)(unsigned)(t + 1) << 32;
#pragma unroll
      for (int rt = 0; rt < 4; ++rt) {
#pragma unroll
        for (int i = 0; i < 4; ++i) {
          unsigned short mb = f2bf(h_own[rt][i]);
          int other = __shfl_xor((int)(unsigned)mb, 1);
          if ((lane & 1) == 0) {
            unsigned pack = (unsigned)mb | (((unsigned)other & 0xffffu) << 16);
            __hip_atomic_store(hd + (rt * 16 + quad * 4 + i) * 128 + (col >> 1),
                               tag | (unsigned long long)pack,
                               __ATOMIC_RELAXED, __HIP_MEMORY_SCOPE_AGENT);
          }
        }
      }
    }

    // ---- eos extraction (byte-packed reg-compare, off critical path) ----
#pragma unroll
    for (int rt = 0; rt < 4; ++rt)
#pragma unroll
      for (int i = 0; i < 4; ++i) {
        if (((tp[rt] >> (8 * i)) & 255) == t + 1) {
          int m = rt * 16 + quad * 4 + i;
          outp[(size_t)m * 256 + col] = h_own[rt][i];
        }
      }
  }
}

// ---------------- warm-start chain GRU: grid 256 = 64 chains x 4 WGs -------------------
// blockIdx remap: xcd = x&7; chain c = (x&7) + 8*(x>>5); wg4 = (x>>3)&3.
// All 4 WGs of a chain share x%8 -> same XCD under round-robin dispatch.
__global__ __launch_bounds__(256, 1) void gru_k(
    const float* __restrict__ w_ih, const float* __restrict__ w_hh,
    const float* __restrict__ b_ih, const float* __restrict__ b_hh,
    const unsigned* __restrict__ Xs, const unsigned* __restrict__ Xq,
    unsigned long long* hbs, unsigned long long* hbq,
    const int* __restrict__ idx_s, const int* __restrict__ qidx,
    float* __restrict__ mem_slots, float* __restrict__ real_q) {
  __shared__ unsigned long long s_h[8192];  // 64 KB double-buffered h tile
  const int tid = threadIdx.x;
  const int x = blockIdx.x;
  const int c = (x & 7) + 8 * (x >> 5);     // chain 0..63
  const int wg4 = (x >> 3) & 3;             // WG within chain
  const int lane = tid & 63;
  const int wave = tid >> 6;
  const int lo = lane & 15;
  const int quad = lane >> 4;
  const int slice = wg4 * 4 + wave;         // 0..15 col-slice of the chain
  const int col = slice * 16 + lo;          // this lane's hidden dim

  // ---- loop-invariant weight B-fragments (bf16) in registers ----
  bf16x8 Bih[3][4], Bhh[3][8];
  for (int g = 0; g < 3; ++g) {
    const float* wr = w_ih + (size_t)(g * 256 + col) * 128;
    for (int kt = 0; kt < 4; ++kt) {
      const float* pp = wr + kt * 32 + quad * 8;
      union { unsigned short us[8]; bf16x8 v; } u;
#pragma unroll
      for (int j = 0; j < 8; ++j) u.us[j] = f2bf(pp[j]);
      Bih[g][kt] = u.v;
    }
    const float* wr2 = w_hh + (size_t)(g * 256 + col) * 256;
    for (int kt = 0; kt < 8; ++kt) {
      const float* pp = wr2 + kt * 32 + quad * 8;
      union { unsigned short us[8]; bf16x8 v; } u;
#pragma unroll
      for (int j = 0; j < 8; ++j) u.us[j] = f2bf(pp[j]);
      Bhh[g][kt] = u.v;
    }
  }
  const float br  = b_ih[col]       + b_hh[col];
  const float bz  = b_ih[256 + col] + b_hh[256 + col];
  const float bin = b_ih[512 + col];
  const float bhn = b_hh[512 + col];

  // ---- story chain c: warm over segment c-1 (c>=1), then segment c ----
  const int tokBase = (c == 0) ? 0 : (c - 1) * 20;
  const int warm = (c == 0) ? 0 : 20;
  const int T = warm + 20;

  {
    const int* eb = idx_s + c * 50;
    int tp[4];
#pragma unroll
    for (int rt = 0; rt < 4; ++rt) {
      int v = 0;
#pragma unroll
      for (int i = 0; i < 4; ++i) {
        int m = rt * 16 + quad * 4 + i;
        int tv = 0;                       // 0 = never fires
        if (m < 50) tv = eb[m] + warm + 1;  // compare vs t+1 (<=40, fits byte)
        v |= tv << (8 * i);
      }
      tp[rt] = v;
    }
    run_chain(Xs, tokBase, T, hbs + (size_t)c * 16384, s_h,
              Bih, Bhh, br, bz, bin, bhn, tp,
              mem_slots + (size_t)c * 50 * 256,
              lane, wave, lo, quad, col);
  }

  // ---- query chain on chain 0's WG quad (story chain 0 is 20 steps; path=40) ----
  if (c == 0) {
    __syncthreads();
    int tp[4];
#pragma unroll
    for (int rt = 0; rt < 4; ++rt) {
      int v = 0;
#pragma unroll
      for (int i = 0; i < 4; ++i)
        v |= (qidx[rt * 16 + quad * 4 + i] + 1) << (8 * i);
      tp[rt] = v;
    }
    run_chain(Xq, 0, 20, hbq, s_h,
              Bih, Bhh, br, bz, bin, bhn, tp, real_q,
              lane, wave, lo, quad, col);
  }
}

// ---------------- mem_key = memory_slots @ w_m^T  [3200,256]x[256,256] ----------------
__global__ __launch_bounds__(256) void memkey_k(const float* __restrict__ slots,
                                                const float* __restrict__ w_m,
                                                float* __restrict__ mem_key) {
  __shared__ float A[4096];
  int tid = threadIdx.x;
  int r0 = blockIdx.x * 16;
  for (int i = tid; i < 4096; i += 256) A[i] = slots[(size_t)r0 * 256 + i];
  __syncthreads();
  float acc[16];
#pragma unroll
  for (int r = 0; r < 16; ++r) acc[r] = 0.f;
  const float* wr = w_m + (size_t)tid * 256;
  for (int k = 0; k < 256; ++k) {
    float wv = wr[k];
#pragma unroll
    for (int r = 0; r < 16; ++r) acc[r] += A[r * 256 + k] * wv;
  }
  for (int r = 0; r < 16; ++r) mem_key[(size_t)(r0 + r) * 256 + tid] = acc[r];
}

// ---------------- 3-hop attention over memory slots (one block per b) ----------------
__global__ __launch_bounds__(256) void hops_k(const float* __restrict__ mem_key,
                                              const float* __restrict__ slots,
                                              const float* __restrict__ rq,
                                              const float* __restrict__ ft_w1,
                                              const float* __restrict__ ft_b1,
                                              const float* __restrict__ ft_w2,
                                              const float* __restrict__ ft_b2,
                                              float* __restrict__ bufs) {
  int b = blockIdx.x;
  int tid = threadIdx.x;
  int lane = tid & 63;
  int wv = tid >> 6;
  __shared__ float ok[256], attn[64], bufl[256], h1[256];
  ok[tid] = rq[(size_t)b * 256 + tid];
  __syncthreads();
  const float* key = mem_key + (size_t)b * 50 * 256;
  const float* slt = slots + (size_t)b * 50 * 256;
  for (int hop = 0; hop < 3; ++hop) {
    for (int m = wv; m < 50; m += 4) {
      const float* kr = key + m * 256;
      float p = kr[lane] * ok[lane] + kr[lane + 64] * ok[lane + 64] +
                kr[lane + 128] * ok[lane + 128] + kr[lane + 192] * ok[lane + 192];
      for (int off = 32; off; off >>= 1) p += __shfl_down(p, off);
      if (lane == 0) attn[m] = p * 0.0625f;   // scale = 1/sqrt(256)
    }
    __syncthreads();
    if (tid == 0) {
      float mx = -1e30f;
      for (int m = 0; m < 50; ++m) mx = fmaxf(mx, attn[m]);
      float sm = 0.f;
      for (int m = 0; m < 50; ++m) { float e = __expf(attn[m] - mx); attn[m] = e; sm += e; }
      float inv = 1.f / sm;
      for (int m = 0; m < 50; ++m) attn[m] *= inv;
    }
    __syncthreads();
    float acc = 0.f;
    for (int m = 0; m < 50; ++m) acc += attn[m] * slt[m * 256 + tid];
    bufl[tid] = acc;
    bufs[(size_t)(b * 3 + hop) * 256 + tid] = acc;
    __syncthreads();
    float a1 = ft_b1[tid];
    const float* wr = ft_w1 + (size_t)tid * 256;
    for (int k = 0; k < 256; ++k) a1 += wr[k] * bufl[k];
    h1[tid] = fmaxf(a1, 0.f);
    __syncthreads();
    float a2 = ft_b2[tid];
    const float* w2r = ft_w2 + (size_t)tid * 256;
    for (int k = 0; k < 256; ++k) a2 += w2r[k] * h1[k];
    __syncthreads();
    ok[tid] = a2;
    __syncthreads();
  }
}

// ---------------- relation layer 1: t1 = relu(comb @ g_w1^T + g_b1) [576,768] ----------------
__global__ __launch_bounds__(256) void g1_k(const float* __restrict__ bufs,
                                            const float* __restrict__ rq,
                                            const float* __restrict__ w,
                                            const float* __restrict__ bias,
                                            float* __restrict__ out) {
  __shared__ float A[4 * 768];
  int tid = threadIdx.x;
  int r0 = blockIdx.x * 4;
  for (int i = tid; i < 4 * 768; i += 256) {
    int row = r0 + i / 768, k = i % 768;
    int bb = row / 9, p = row % 9;
    float v;
    if (k < 256)      v = bufs[(size_t)(bb * 3 + p % 3) * 256 + k];
    else if (k < 512) v = bufs[(size_t)(bb * 3 + p / 3) * 256 + (k - 256)];
    else              v = rq[(size_t)bb * 256 + (k - 512)];
    A[i] = v;
  }
  __syncthreads();
  for (int cc = 0; cc < 3; ++cc) {
    int c = cc * 256 + tid;
    float a0 = 0.f, a1 = 0.f, a2 = 0.f, a3 = 0.f;
    const float* wr = w + (size_t)c * 768;
    for (int k = 0; k < 768; ++k) {
      float wvl = wr[k];
      a0 += A[k] * wvl; a1 += A[768 + k] * wvl;
      a2 += A[1536 + k] * wvl; a3 += A[2304 + k] * wvl;
    }
    float bv = bias[c];
    out[(size_t)(r0 + 0) * 768 + c] = fmaxf(a0 + bv, 0.f);
    out[(size_t)(r0 + 1) * 768 + c] = fmaxf(a1 + bv, 0.f);
    out[(size_t)(r0 + 2) * 768 + c] = fmaxf(a2 + bv, 0.f);
    out[(size_t)(r0 + 3) * 768 + c] = fmaxf(a3 + bv, 0.f);
  }
}

// ---------------- relation layer 2: t2 = relu(t1 @ g_w2^T + g_b2) ----------------
__global__ __launch_bounds__(256) void g2_k(const float* __restrict__ t1,
                                            const float* __restrict__ w,
                                            const float* __restrict__ bias,
                                            float* __restrict__ out) {
  __shared__ float A[4 * 768];
  int tid = threadIdx.x;
  int r0 = blockIdx.x * 4;
  for (int i = tid; i < 4 * 768; i += 256) A[i] = t1[(size_t)r0 * 768 + i];
  __syncthreads();
  for (int cc = 0; cc < 3; ++cc) {
    int c = cc * 256 + tid;
    float a0 = 0.f, a1 = 0.f, a2 = 0.f, a3 = 0.f;
    const float* wr = w + (size_t)c * 768;
    for (int k = 0; k < 768; ++k) {
      float wvl = wr[k];
      a0 += A[k] * wvl; a1 += A[768 + k] * wvl;
      a2 += A[1536 + k] * wvl; a3 += A[2304 + k] * wvl;
    }
    float bv = bias[c];
    out[(size_t)(r0 + 0) * 768 + c] = fmaxf(a0 + bv, 0.f);
    out[(size_t)(r0 + 1) * 768 + c] = fmaxf(a1 + bv, 0.f);
    out[(size_t)(r0 + 2) * 768 + c] = fmaxf(a2 + bv, 0.f);
    out[(size_t)(r0 + 3) * 768 + c] = fmaxf(a3 + bv, 0.f);
  }
}

// ---------------- g-sum + f MLP -> reason [64,256] ----------------
__global__ __launch_bounds__(256) void reason_k(const float* __restrict__ t2,
                                                const float* __restrict__ f_w1,
                                                const float* __restrict__ f_b1,
                                                const float* __restrict__ f_w2,
                                                const float* __restrict__ f_b2,
                                                float* __restrict__ reason) {
  int b = blockIdx.x;
  int tid = threadIdx.x;
  __shared__ float gs[768], h1[768];
  for (int j = tid; j < 768; j += 256) {
    float s = 0.f;
    for (int p = 0; p < 9; ++p) s += t2[(size_t)(b * 9 + p) * 768 + j];
    gs[j] = s;
  }
  __syncthreads();
  for (int jc = 0; jc < 3; ++jc) {
    int j = jc * 256 + tid;
    float a = f_b1[j];
    const float* wr = f_w1 + (size_t)j * 768;
    for (int k = 0; k < 768; ++k) a += wr[k] * gs[k];
    h1[j] = fmaxf(a, 0.f);
  }
  __syncthreads();
  {
    int j = tid;
    float a = f_b2[j];
    const float* wr = f_w2 + (size_t)j * 768;
    for (int k = 0; k < 768; ++k) a += wr[k] * h1[k];
    reason[(size_t)b * 256 + j] = a;
  }
}

// ---------------- out = reason @ v_w^T  [64,50000] ----------------
__global__ __launch_bounds__(256) void vocab_k(const float* __restrict__ reason,
                                               const float* __restrict__ v_w,
                                               float* __restrict__ out) {
  __shared__ float A[32 * 256];
  int tid = threadIdx.x;
  int c = blockIdx.x * 256 + tid;
  for (int bc = 0; bc < 2; ++bc) {
    for (int i = tid; i < 32 * 256; i += 256) A[i] = reason[bc * 32 * 256 + i];
    __syncthreads();
    if (c < 50000) {
      float acc[32];
#pragma unroll
      for (int r = 0; r < 32; ++r) acc[r] = 0.f;
      const float* wr = v_w + (size_t)c * 256;
      for (int k = 0; k < 256; ++k) {
        float wvl = wr[k];
#pragma unroll
        for (int r = 0; r < 32; ++r) acc[r] += A[r * 256 + k] * wvl;
      }
      for (int r = 0; r < 32; ++r) out[(size_t)(bc * 32 + r) * 50000 + c] = acc[r];
    }
    __syncthreads();
  }
}

// ---------------- launch ----------------
extern "C" void kernel_launch(void* const* d_in, const int* in_sizes, int n_in,
                              void* d_out, int out_size, void* d_ws, size_t ws_size,
                              hipStream_t stream) {
  (void)in_sizes; (void)n_in; (void)out_size; (void)ws_size;
  const int*   story = (const int*)d_in[0];
  const int*   query = (const int*)d_in[1];
  const float* embed = (const float*)d_in[2];
  const float* w_ih  = (const float*)d_in[3];
  const float* w_hh  = (const float*)d_in[4];
  const float* b_ih  = (const float*)d_in[5];
  const float* b_hh  = (const float*)d_in[6];
  const float* w_m   = (const float*)d_in[7];
  const float* ft_w1 = (const float*)d_in[8];
  const float* ft_b1 = (const float*)d_in[9];
  const float* ft_w2 = (const float*)d_in[10];
  const float* ft_b2 = (const float*)d_in[11];
  const float* g_w1  = (const float*)d_in[12];
  const float* g_b1  = (const float*)d_in[13];
  const float* g_w2  = (const float*)d_in[14];
  const float* g_b2  = (const float*)d_in[15];
  const float* f_w1  = (const float*)d_in[16];
  const float* f_b1  = (const float*)d_in[17];
  const float* f_w2  = (const float*)d_in[18];
  const float* f_b2  = (const float*)d_in[19];
  const float* v_w   = (const float*)d_in[20];
  float* out = (float*)d_out;

  char* ws = (char*)d_ws;
  unsigned* Xs = (unsigned*)(ws + 0);               // 20,971,520 B
  unsigned* Xq = (unsigned*)(ws + 20971520);        //    327,680 B
  unsigned long long* hbs =
      (unsigned long long*)(ws + 21299200);         //  8,388,608 B (64 x 16384 u64)
  unsigned long long* hbq =
      (unsigned long long*)(ws + 29687808);         //    131,072 B
  int*      idx_s   = (int*)(ws + 29818880);        //     12,800 B
  int*      qidx    = (int*)(ws + 29831680);        //        256 B
  float*    mslots  = (float*)(ws + 29831936);      //  3,276,800 B
  float*    real_q  = (float*)(ws + 33108736);      //     65,536 B  (end ~33.2 MB)
  // post-GRU overlay inside the (dead) Xs region:
  float*    mem_key = (float*)(ws + 0);             //  3,276,800 B
  float*    bufs    = (float*)(ws + 3276800);       //    196,608 B
  float*    t1      = (float*)(ws + 3473408);       //  1,769,472 B
  float*    t2      = (float*)(ws + 5242880);       //  1,769,472 B
  float*    reason  = (float*)(ws + 7012352);       //     65,536 B

  // prep: zero hbs+hbq (8,519,680 B = 532,480 u32x4 -> 2080 blocks) + eos idx (13)
  prep_k<<<2093, 256, 0, stream>>>((u32x4*)(ws + 21299200), 532480,
                                   story, query, idx_s, qidx);
  gather_k<<<20800, 256, 0, stream>>>(story, query, embed, Xs, Xq);
  gru_k<<<256, 256, 0, stream>>>(w_ih, w_hh, b_ih, b_hh, Xs, Xq, hbs, hbq,
                                 idx_s, qidx, mslots, real_q);
  memkey_k<<<200, 256, 0, stream>>>(mslots, w_m, mem_key);
  hops_k<<<64, 256, 0, stream>>>(mem_key, mslots, real_q,
                                 ft_w1, ft_b1, ft_w2, ft_b2, bufs);
  g1_k<<<144, 256, 0, stream>>>(bufs, real_q, g_w1, g_b1, t1);
  g2_k<<<144, 256, 0, stream>>>(t1, g_w2, g_b2, t2);
  reason_k<<<64, 256, 0, stream>>>(t2, f_w1, f_b1, f_w2, f_b2, reason);
  vocab_k<<<196, 256, 0, stream>>>(reason, v_w, out);
}